// Round 18
// baseline (536.409 us; speedup 1.0000x reference)
//
#include <hip/hip_runtime.h>
#include <cstdint>
#include <cstddef>

#define DIV_UP(a, b) (((a) + (b) - 1) / (b))

typedef unsigned short u16;
typedef __attribute__((ext_vector_type(8))) short bf16x8;
typedef __attribute__((ext_vector_type(4))) float f32x4;

// ---------------- bf16 helpers (RNE) ----------------

__device__ __forceinline__ float asf(unsigned int u) {
  float f;
  __builtin_memcpy(&f, &u, 4);
  return f;
}
__device__ __forceinline__ unsigned int asu(float f) {
  unsigned int u;
  __builtin_memcpy(&u, &f, 4);
  return u;
}
__device__ __forceinline__ float b2f(u16 u) { return asf(((unsigned int)u) << 16); }
__device__ __forceinline__ u16 f2b(float f) {
  unsigned int x = asu(f);
  return (u16)((x + 0x7FFFu + ((x >> 16) & 1u)) >> 16);
}
__device__ __forceinline__ unsigned int pack2(float lo, float hi) {
  return ((unsigned int)f2b(hi) << 16) | (unsigned int)f2b(lo);
}

// ---------------- CSR build ----------------

// rank[e] = arrival order within dst bucket (atomic's return value).
// 4 edges/thread = 4 independent atomic->write chains (r15: chain ILP gave
// 1.35x on the same latency-bound atomic pattern in fill).
__global__ void count_kernel(const int* __restrict__ dst, int* __restrict__ cnt,
                             int* __restrict__ rank, int E, int q) {
  int i = blockIdx.x * blockDim.x + threadIdx.x;
  int e0 = i, e1 = i + q, e2 = i + 2 * q, e3 = i + 3 * q;
  bool v0 = e0 < q, v1 = e1 < 2 * q, v2 = e2 < 3 * q, v3 = e3 < E;
  int d0 = 0, d1 = 0, d2 = 0, d3 = 0;
  if (v0) d0 = dst[e0];
  if (v1) d1 = dst[e1];
  if (v2) d2 = dst[e2];
  if (v3) d3 = dst[e3];
  int r0 = 0, r1 = 0, r2 = 0, r3 = 0;
  if (v0) r0 = atomicAdd(&cnt[d0], 1);
  if (v1) r1 = atomicAdd(&cnt[d1], 1);
  if (v2) r2 = atomicAdd(&cnt[d2], 1);
  if (v3) r3 = atomicAdd(&cnt[d3], 1);
  if (v0) rank[e0] = r0;
  if (v1) rank[e1] = r1;
  if (v2) rank[e2] = r2;
  if (v3) rank[e3] = r3;
}

__global__ void scan1_kernel(const int* __restrict__ cnt, int* __restrict__ rowstart,
                             int* __restrict__ bsums, int n) {
  __shared__ int sh[256];
  const int tid = threadIdx.x;
  const int base = blockIdx.x * 1024 + tid * 4;
  int c0 = (base + 0 < n) ? cnt[base + 0] : 0;
  int c1 = (base + 1 < n) ? cnt[base + 1] : 0;
  int c2 = (base + 2 < n) ? cnt[base + 2] : 0;
  int c3 = (base + 3 < n) ? cnt[base + 3] : 0;
  sh[tid] = c0 + c1 + c2 + c3;
  __syncthreads();
  for (int off = 1; off < 256; off <<= 1) {
    int v = (tid >= off) ? sh[tid - off] : 0;
    __syncthreads();
    sh[tid] += v;
    __syncthreads();
  }
  int excl = (tid > 0) ? sh[tid - 1] : 0;
  if (base + 0 < n) rowstart[base + 0] = excl;
  if (base + 1 < n) rowstart[base + 1] = excl + c0;
  if (base + 2 < n) rowstart[base + 2] = excl + c0 + c1;
  if (base + 3 < n) rowstart[base + 3] = excl + c0 + c1 + c2;
  if (tid == 255) bsums[blockIdx.x] = sh[255];
}

__global__ void scan2_kernel(int* __restrict__ bsums, int nb) {
  __shared__ int sh[512];
  const int tid = threadIdx.x;
  int v = (tid < nb) ? bsums[tid] : 0;
  sh[tid] = v;
  __syncthreads();
  for (int off = 1; off < 512; off <<= 1) {
    int t = (tid >= off) ? sh[tid - off] : 0;
    __syncthreads();
    sh[tid] += t;
    __syncthreads();
  }
  int excl = (tid > 0) ? sh[tid - 1] : 0;
  if (tid < nb) bsums[tid] = excl;
}

__global__ void scan3_kernel(int* __restrict__ rowstart, const int* __restrict__ bsums,
                             const int* __restrict__ cnt, float* __restrict__ dinv,
                             int n, int E) {
  int i = blockIdx.x * blockDim.x + threadIdx.x;
  if (i < n) {
    rowstart[i] = rowstart[i] + bsums[i >> 10];
    dinv[i] = rsqrtf((float)cnt[i] + 1.0f);  // +1 for self-loop
  }
  if (i == 0) rowstart[n] = E;
}

// atomic-free: pos = rowstart[d] + rank[e]; one fire-and-forget 8B scatter.
__global__ void fill_kernel(const int* __restrict__ src, const int* __restrict__ dst,
                            const int* __restrict__ rank, const int* __restrict__ rowstart,
                            const float* __restrict__ dinv, uint2* __restrict__ colew,
                            int E) {
  int e = blockIdx.x * blockDim.x + threadIdx.x;
  if (e < E) {
    int s = src[e], d = dst[e];
    float w = dinv[s] * dinv[d];
    int pos = rowstart[d] + rank[e];
    colew[pos] = make_uint2((unsigned int)s, asu(w));
  }
}

// ---------------- W prep: fp32 [K,NC] -> transposed bf16 [NC*K] ----------------

__global__ void prep_w(const float* __restrict__ W1, const float* __restrict__ W2,
                       const float* __restrict__ W3, u16* __restrict__ Wt1,
                       u16* __restrict__ Wt2, u16* __restrict__ Wt3) {
  int i = blockIdx.x * blockDim.x + threadIdx.x;
  float w;
  u16* dst;
  int idx;
  if (i < 8192) {                       // W1 [64,128] -> Wt1 [128][64]
    int c = i >> 6, k = i & 63;
    w = W1[k * 128 + c];
    dst = Wt1; idx = i;
  } else if (i < 24576) {               // W2 [128,128] -> Wt2 [128][128]
    int j = i - 8192;
    int c = j >> 7, k = j & 127;
    w = W2[k * 128 + c];
    dst = Wt2; idx = j;
  } else if (i < 32768) {               // W3 [128,64] -> Wt3 [64][128]
    int j = i - 24576;
    int c = j >> 7, k = j & 127;
    w = W3[k * 64 + c];
    dst = Wt3; idx = j;
  } else {
    return;
  }
  dst[idx] = f2b(w);
}

// ---------------- x fp32 -> bf16 ----------------

__global__ void conv_x(const float* __restrict__ x, u16* __restrict__ xb, int n8) {
  int i = blockIdx.x * blockDim.x + threadIdx.x;
  if (i >= n8) return;
  const float4* p = reinterpret_cast<const float4*>(x) + (size_t)i * 2;
  float4 a = p[0], b = p[1];
  uint4 o;
  o.x = pack2(a.x, a.y);
  o.y = pack2(a.z, a.w);
  o.z = pack2(b.x, b.y);
  o.w = pack2(b.z, b.w);
  *reinterpret_cast<uint4*>(xb + (size_t)i * 8) = o;
}

// ---------------- aggregation: 16 lanes per node, masked-quad gathers ----------------
// Poisson(4) degrees: uniform predicated-quad loop -> every row of deg 1..4
// finishes its edges in ONE batch of 4 parallel gathers (invalid slots gather
// the just-fetched a0.x row -- L1-hot -- with weight 0); no serialized tail.

template <int EPL> struct Raw;
template <> struct Raw<8> { uint4 v; };
template <> struct Raw<4> { uint2 v; };

template <int EPL>
__device__ __forceinline__ Raw<EPL> ldraw(const u16* p);
template <>
__device__ __forceinline__ Raw<8> ldraw<8>(const u16* p) {
  return {*reinterpret_cast<const uint4*>(p)};
}
template <>
__device__ __forceinline__ Raw<4> ldraw<4>(const u16* p) {
  return {*reinterpret_cast<const uint2*>(p)};
}

template <int EPL>
__device__ __forceinline__ void rfma(float* a, float w, Raw<EPL> r) {
  if constexpr (EPL == 8) {
    a[0] += w * asf(r.v.x << 16); a[1] += w * asf(r.v.x & 0xFFFF0000u);
    a[2] += w * asf(r.v.y << 16); a[3] += w * asf(r.v.y & 0xFFFF0000u);
    a[4] += w * asf(r.v.z << 16); a[5] += w * asf(r.v.z & 0xFFFF0000u);
    a[6] += w * asf(r.v.w << 16); a[7] += w * asf(r.v.w & 0xFFFF0000u);
  } else {
    a[0] += w * asf(r.v.x << 16); a[1] += w * asf(r.v.x & 0xFFFF0000u);
    a[2] += w * asf(r.v.y << 16); a[3] += w * asf(r.v.y & 0xFFFF0000u);
  }
}

template <int F, bool BR>  // F = 64 or 128; bf16 in/out
__global__ __launch_bounds__(256) void agg_kernel(const u16* __restrict__ v,
                                                  const float* __restrict__ dinv,
                                                  const int* __restrict__ rowstart,
                                                  const uint2* __restrict__ colew,
                                                  const float* __restrict__ bias,
                                                  u16* __restrict__ out, int n) {
  constexpr int EPL = F / 16;
  const int node = (int)((blockIdx.x * blockDim.x + threadIdx.x) >> 4);
  const int l = threadIdx.x & 15;
  if (node >= n) return;
  const size_t loff = (size_t)l * EPL;
  float acc[EPL];
#pragma unroll
  for (int j = 0; j < EPL; ++j) acc[j] = 0.0f;
  const float di = dinv[node];
  rfma<EPL>(acc, di * di, ldraw<EPL>(v + (size_t)node * F + loff));

  int k = rowstart[node];
  const int r1 = rowstart[node + 1];
  while (k < r1) {
    const int rem = r1 - k;
    uint2 a0 = colew[k];
    uint2 a1 = (rem > 1) ? colew[k + 1] : make_uint2(a0.x, 0u);
    uint2 a2 = (rem > 2) ? colew[k + 2] : make_uint2(a0.x, 0u);
    uint2 a3 = (rem > 3) ? colew[k + 3] : make_uint2(a0.x, 0u);
    Raw<EPL> g0 = ldraw<EPL>(v + (size_t)a0.x * F + loff);
    Raw<EPL> g1 = ldraw<EPL>(v + (size_t)a1.x * F + loff);
    Raw<EPL> g2 = ldraw<EPL>(v + (size_t)a2.x * F + loff);
    Raw<EPL> g3 = ldraw<EPL>(v + (size_t)a3.x * F + loff);
    rfma<EPL>(acc, asf(a0.y), g0);
    rfma<EPL>(acc, asf(a1.y), g1);
    rfma<EPL>(acc, asf(a2.y), g2);
    rfma<EPL>(acc, asf(a3.y), g3);
    k += 4;
  }

  if (BR) {
#pragma unroll
    for (int j = 0; j < EPL; ++j) acc[j] = fmaxf(acc[j] + bias[l * EPL + j], 0.0f);
  }
  if constexpr (EPL == 8) {
    uint4 o;
    o.x = pack2(acc[0], acc[1]);
    o.y = pack2(acc[2], acc[3]);
    o.z = pack2(acc[4], acc[5]);
    o.w = pack2(acc[6], acc[7]);
    *reinterpret_cast<uint4*>(out + (size_t)node * F + loff) = o;
  } else {
    uint2 o;
    o.x = pack2(acc[0], acc[1]);
    o.y = pack2(acc[2], acc[3]);
    *reinterpret_cast<uint2*>(out + (size_t)node * F + loff) = o;
  }
}

// ---------------- graph boundaries (batch sorted) + segmented mean pool ----------------

__global__ void gbounds_kernel(const int* __restrict__ batch, int* __restrict__ gstart,
                               int N, int G) {
  int g = blockIdx.x * blockDim.x + threadIdx.x;
  if (g > G) return;
  int lo = 0, hi = N;
  while (lo < hi) {
    int mid = (lo + hi) >> 1;
    if (batch[mid] < g) lo = mid + 1; else hi = mid;
  }
  gstart[g] = lo;
}

__global__ __launch_bounds__(256) void pool_kernel(const u16* __restrict__ h3,
                                                   const int* __restrict__ gstart,
                                                   float* __restrict__ pooled, int G) {
  int g = (blockIdx.x * blockDim.x + threadIdx.x) >> 6;
  int lane = threadIdx.x & 63;
  if (g >= G) return;
  int s = gstart[g], e = gstart[g + 1];
  float a0 = 0.f, a1 = 0.f, a2 = 0.f, a3 = 0.f;
  int i = s;
  for (; i + 4 <= e; i += 4) {
    a0 += b2f(h3[(size_t)(i + 0) * 64 + lane]);
    a1 += b2f(h3[(size_t)(i + 1) * 64 + lane]);
    a2 += b2f(h3[(size_t)(i + 2) * 64 + lane]);
    a3 += b2f(h3[(size_t)(i + 3) * 64 + lane]);
  }
  for (; i < e; ++i) a0 += b2f(h3[(size_t)i * 64 + lane]);
  float acc = (a0 + a1) + (a2 + a3);
  pooled[(size_t)g * 64 + lane] = acc / fmaxf((float)(e - s), 1.0f);
}

// ---------------- MFMA GEMM: out = A @ W + bias (+relu) ----------
// r13 config (best measured): 256 thr / 4 waves, __launch_bounds__(256,2),
// 128-row tile, grid-stride, hi-only bf16 W in typed LDS (XOR-swizzled),
// LDS out-staging epilogue with uint4 16B global stores.

template <int K, int NC, bool RELU>
__global__ __launch_bounds__(256, 2) void gemm_mfma(const u16* __restrict__ A,
                                                    const u16* __restrict__ Wt,
                                                    const float* __restrict__ bias,
                                                    u16* __restrict__ out, int n) {
  constexpr int CHK = K / 8;        // 16B chunks per W row
  constexpr int OST = NC + 8;       // padded out-stage row stride (u16)
  __shared__ bf16x8 Wl8[NC * CHK];
  __shared__ float biasl[NC];
  __shared__ u16 obuf[4 * 16 * OST];
  for (int i = threadIdx.x; i < NC * CHK; i += 256) {
    int c = i / CHK, kc = i - c * CHK;
    uint4 raw = *reinterpret_cast<const uint4*>(Wt + (size_t)c * K + kc * 8);
    Wl8[c * CHK + (kc ^ (c & 7))] = __builtin_bit_cast(bf16x8, raw);
  }
  if (threadIdx.x < NC) biasl[threadIdx.x] = bias ? bias[threadIdx.x] : 0.0f;
  __syncthreads();

  const int wid = threadIdx.x >> 6;   // 0..3
  const int lane = threadIdx.x & 63;
  const int lr = lane & 15;
  const int lg = lane >> 4;           // 0..3
  const int ntiles = DIV_UP(n, 128);
  u16* ob = obuf + wid * (16 * OST);

  for (int t = blockIdx.x; t < ntiles; t += (int)gridDim.x) {
    const int row0 = t * 128 + wid * 32;

    bf16x8 af[2][K / 32];
#pragma unroll
    for (int rep = 0; rep < 2; ++rep) {
      int ar = row0 + rep * 16 + lr;
      if (ar >= n) ar = n - 1;  // clamp; stores guarded
      const u16* ap = A + (size_t)ar * K + lg * 8;
#pragma unroll
      for (int ks = 0; ks < K / 32; ++ks) af[rep][ks] = *reinterpret_cast<const bf16x8*>(ap + ks * 32);
    }

    f32x4 acc[2][NC / 16];
#pragma unroll
    for (int rep = 0; rep < 2; ++rep)
#pragma unroll
      for (int ct = 0; ct < NC / 16; ++ct) acc[rep][ct] = {0.f, 0.f, 0.f, 0.f};

#pragma unroll
    for (int ks = 0; ks < K / 32; ++ks) {
#pragma unroll
      for (int ct = 0; ct < NC / 16; ++ct) {
        const int c = ct * 16 + lr;
        const int slot = (ks * 4 + lg) ^ (c & 7);
        bf16x8 bh = Wl8[c * CHK + slot];
        acc[0][ct] = __builtin_amdgcn_mfma_f32_16x16x32_bf16(af[0][ks], bh, acc[0][ct], 0, 0, 0);
        acc[1][ct] = __builtin_amdgcn_mfma_f32_16x16x32_bf16(af[1][ks], bh, acc[1][ct], 0, 0, 0);
      }
    }

#pragma unroll
    for (int rep = 0; rep < 2; ++rep) {
      // stage this rep's 16 x NC tile into LDS (scalar u16 writes, no vmcnt)
#pragma unroll
      for (int ct = 0; ct < NC / 16; ++ct) {
        const int c = ct * 16 + lr;
        const float b = biasl[c];
#pragma unroll
        for (int v = 0; v < 4; ++v) {
          float o = acc[rep][ct][v] + b;
          if (RELU) o = fmaxf(o, 0.0f);
          ob[(lg * 4 + v) * OST + c] = f2b(o);
        }
      }
      asm volatile("s_waitcnt lgkmcnt(0)" ::: "memory");
      // read back row-major, wide 16B global stores
      const int rrow = lane >> 2;   // 0..15
      const int chk0 = lane & 3;    // 0..3
      const int grow = row0 + rep * 16 + rrow;
      if (grow < n) {
        u16* gp = out + (size_t)grow * NC;
#pragma unroll
        for (int it = 0; it < NC / 32; ++it) {
          const int ch = it * 4 + chk0;
          uint4 val = *reinterpret_cast<const uint4*>(ob + rrow * OST + ch * 8);
          *reinterpret_cast<uint4*>(gp + ch * 8) = val;
        }
      }
      asm volatile("s_waitcnt lgkmcnt(0)" ::: "memory");
    }
  }
}

// ---------------- 5-task MLP heads ----------------

__global__ __launch_bounds__(256) void heads_kernel(const float* __restrict__ pooled,
                                                    const float* __restrict__ Wa,
                                                    const float* __restrict__ ba,
                                                    const float* __restrict__ Wb,
                                                    const float* __restrict__ bb,
                                                    float* __restrict__ outp, int G) {
  int gid = blockIdx.x * blockDim.x + threadIdx.x;
  if (gid >= 5 * G) return;
  int g = gid % G;
  int t = gid / G;
  const float* Wat = Wa + (size_t)t * 64 * 32;
  float hid[32];
#pragma unroll
  for (int j = 0; j < 32; ++j) hid[j] = ba[t * 32 + j];
  for (int d = 0; d < 64; ++d) {
    float pd = pooled[(size_t)g * 64 + d];
#pragma unroll
    for (int j = 0; j < 32; ++j) hid[j] += pd * Wat[d * 32 + j];
  }
  float o = bb[t];
#pragma unroll
  for (int j = 0; j < 32; ++j) o += fmaxf(hid[j], 0.0f) * Wb[t * 32 + j];
  outp[(size_t)t * G + g] = o;
}

// ---------------- launch ----------------

extern "C" void kernel_launch(void* const* d_in, const int* in_sizes, int n_in,
                              void* d_out, int out_size, void* d_ws, size_t ws_size,
                              hipStream_t stream) {
  (void)n_in;
  (void)ws_size;
  const float* x  = (const float*)d_in[0];
  const int* ei   = (const int*)d_in[1];
  const int* batch = (const int*)d_in[2];
  const float* W1 = (const float*)d_in[3];
  const float* b1 = (const float*)d_in[4];
  const float* W2 = (const float*)d_in[5];
  const float* b2 = (const float*)d_in[6];
  const float* W3 = (const float*)d_in[7];
  const float* b3 = (const float*)d_in[8];
  const float* Wa = (const float*)d_in[9];
  const float* ba = (const float*)d_in[10];
  const float* Wb = (const float*)d_in[11];
  const float* bb = (const float*)d_in[12];
  float* out = (float*)d_out;

  const int N = in_sizes[0] / 64;
  const int E = in_sizes[1] / 2;
  const int G = out_size / 5;
  const int* src = ei;
  const int* dst = ei + E;

  char* ws = (char*)d_ws;
  size_t off = 0;
  auto alloc = [&](size_t bytes) -> char* {
    char* p = ws + off;
    off = (off + bytes + 255) & ~(size_t)255;
    return p;
  };
  int* cnt      = (int*)alloc((size_t)N * 4);
  int* rowstart = (int*)alloc((size_t)(N + 1) * 4);
  int* rank     = (int*)alloc((size_t)E * 4);
  uint2* colew  = (uint2*)alloc((size_t)E * 8);
  float* dinv   = (float*)alloc((size_t)N * 4);
  const int nchunks = DIV_UP(N, 1024);  // 391 for N=400000 (<= 512)
  int* bsums    = (int*)alloc((size_t)nchunks * 4);
  int* gstart   = (int*)alloc((size_t)(G + 1) * 4);
  float* pooled = (float*)alloc((size_t)G * 64 * 4);
  u16* Wt1      = (u16*)alloc(8192 * 2);
  u16* Wt2      = (u16*)alloc(16384 * 2);
  u16* Wt3      = (u16*)alloc(8192 * 2);
  const size_t act_elems = (size_t)N * 128;
  u16* bufA     = (u16*)alloc(act_elems * 2);
  u16* bufB     = (u16*)alloc(act_elems * 2);

  hipMemsetAsync(cnt, 0, (size_t)N * 4, stream);

  const int qc = (E + 3) / 4;
  count_kernel<<<DIV_UP(qc, 256), 256, 0, stream>>>(dst, cnt, rank, E, qc);
  scan1_kernel<<<nchunks, 256, 0, stream>>>(cnt, rowstart, bsums, N);
  scan2_kernel<<<1, 512, 0, stream>>>(bsums, nchunks);
  scan3_kernel<<<DIV_UP(N, 256), 256, 0, stream>>>(rowstart, bsums, cnt, dinv, N, E);
  fill_kernel<<<DIV_UP(E, 256), 256, 0, stream>>>(src, dst, rank, rowstart, dinv, colew, E);
  prep_w<<<128, 256, 0, stream>>>(W1, W2, W3, Wt1, Wt2, Wt3);
  gbounds_kernel<<<DIV_UP(G + 1, 256), 256, 0, stream>>>(batch, gstart, N, G);

  // xb (bf16 x) lives in bufA's first N*64 entries (dead before h1 is written).
  u16* xb = bufA;
  conv_x<<<DIV_UP(N * 8, 256), 256, 0, stream>>>(x, xb, N * 8);

  const int aggblocks = DIV_UP(N, 16);
  // t1 [N,64] in bufB; h1 [N,128] in bufA; t2 [N,128] in bufB; h2 [N,128] in bufA;
  // hw3 [N,64] in bufB; h3 [N,64] in bufA.
  agg_kernel<64, false><<<aggblocks, 256, 0, stream>>>(
      xb, dinv, rowstart, colew, nullptr, bufB, N);
  gemm_mfma<64, 128, true><<<512, 256, 0, stream>>>(bufB, Wt1, b1, bufA, N);
  agg_kernel<128, false><<<aggblocks, 256, 0, stream>>>(
      bufA, dinv, rowstart, colew, nullptr, bufB, N);
  gemm_mfma<128, 128, true><<<512, 256, 0, stream>>>(bufB, Wt2, b2, bufA, N);
  gemm_mfma<128, 64, false><<<512, 256, 0, stream>>>(bufA, Wt3, nullptr, bufB, N);
  agg_kernel<64, true><<<aggblocks, 256, 0, stream>>>(
      bufB, dinv, rowstart, colew, b3, bufA, N);
  pool_kernel<<<DIV_UP(G, 4), 256, 0, stream>>>(bufA, gstart, pooled, G);
  heads_kernel<<<DIV_UP(5 * G, 256), 256, 0, stream>>>(pooled, Wa, ba, Wb, bb, out, G);
}

// Round 19
// 521.115 us; speedup vs baseline: 1.0293x; 1.0293x over previous
//
#include <hip/hip_runtime.h>
#include <cstdint>
#include <cstddef>

#define DIV_UP(a, b) (((a) + (b) - 1) / (b))

typedef unsigned short u16;
typedef __attribute__((ext_vector_type(8))) short bf16x8;
typedef __attribute__((ext_vector_type(4))) float f32x4;

// ---------------- bf16 helpers (RNE) ----------------

__device__ __forceinline__ float asf(unsigned int u) {
  float f;
  __builtin_memcpy(&f, &u, 4);
  return f;
}
__device__ __forceinline__ unsigned int asu(float f) {
  unsigned int u;
  __builtin_memcpy(&u, &f, 4);
  return u;
}
__device__ __forceinline__ float b2f(u16 u) { return asf(((unsigned int)u) << 16); }
__device__ __forceinline__ u16 f2b(float f) {
  unsigned int x = asu(f);
  return (u16)((x + 0x7FFFu + ((x >> 16) & 1u)) >> 16);
}
__device__ __forceinline__ unsigned int pack2(float lo, float hi) {
  return ((unsigned int)f2b(hi) << 16) | (unsigned int)f2b(lo);
}

// ---------------- CSR build ----------------

// rank[e] = this edge's arrival order within its dst bucket (the atomic's
// return value). All atomic work lives here; fill is atomic-free.
// NOTE r18: 4-edge strided ILP here REGRESSED (broke dst coalescing) — keep
// 1 edge/thread.
__global__ void count_kernel(const int* __restrict__ dst, int* __restrict__ cnt,
                             int* __restrict__ rank, int E) {
  int e = blockIdx.x * blockDim.x + threadIdx.x;
  if (e < E) rank[e] = atomicAdd(&cnt[dst[e]], 1);
}

__global__ void scan1_kernel(const int* __restrict__ cnt, int* __restrict__ rowstart,
                             int* __restrict__ bsums, int n) {
  __shared__ int sh[256];
  const int tid = threadIdx.x;
  const int base = blockIdx.x * 1024 + tid * 4;
  int c0 = (base + 0 < n) ? cnt[base + 0] : 0;
  int c1 = (base + 1 < n) ? cnt[base + 1] : 0;
  int c2 = (base + 2 < n) ? cnt[base + 2] : 0;
  int c3 = (base + 3 < n) ? cnt[base + 3] : 0;
  sh[tid] = c0 + c1 + c2 + c3;
  __syncthreads();
  for (int off = 1; off < 256; off <<= 1) {
    int v = (tid >= off) ? sh[tid - off] : 0;
    __syncthreads();
    sh[tid] += v;
    __syncthreads();
  }
  int excl = (tid > 0) ? sh[tid - 1] : 0;
  if (base + 0 < n) rowstart[base + 0] = excl;
  if (base + 1 < n) rowstart[base + 1] = excl + c0;
  if (base + 2 < n) rowstart[base + 2] = excl + c0 + c1;
  if (base + 3 < n) rowstart[base + 3] = excl + c0 + c1 + c2;
  if (tid == 255) bsums[blockIdx.x] = sh[255];
}

__global__ void scan2_kernel(int* __restrict__ bsums, int nb) {
  __shared__ int sh[512];
  const int tid = threadIdx.x;
  int v = (tid < nb) ? bsums[tid] : 0;
  sh[tid] = v;
  __syncthreads();
  for (int off = 1; off < 512; off <<= 1) {
    int t = (tid >= off) ? sh[tid - off] : 0;
    __syncthreads();
    sh[tid] += t;
    __syncthreads();
  }
  int excl = (tid > 0) ? sh[tid - 1] : 0;
  if (tid < nb) bsums[tid] = excl;
}

__global__ void scan3_kernel(int* __restrict__ rowstart, const int* __restrict__ bsums,
                             const int* __restrict__ cnt, float* __restrict__ dinv,
                             int n, int E) {
  int i = blockIdx.x * blockDim.x + threadIdx.x;
  if (i < n) {
    rowstart[i] = rowstart[i] + bsums[i >> 10];
    dinv[i] = rsqrtf((float)cnt[i] + 1.0f);  // +1 for self-loop
  }
  if (i == 0) rowstart[n] = E;
}

// atomic-free: pos = rowstart[d] + rank[e]; one fire-and-forget 8B scatter.
__global__ void fill_kernel(const int* __restrict__ src, const int* __restrict__ dst,
                            const int* __restrict__ rank, const int* __restrict__ rowstart,
                            const float* __restrict__ dinv, uint2* __restrict__ colew,
                            int E) {
  int e = blockIdx.x * blockDim.x + threadIdx.x;
  if (e < E) {
    int s = src[e], d = dst[e];
    float w = dinv[s] * dinv[d];
    int pos = rowstart[d] + rank[e];
    colew[pos] = make_uint2((unsigned int)s, asu(w));
  }
}

// ---------------- W prep: fp32 [K,NC] -> transposed bf16 [NC*K] ----------------

__global__ void prep_w(const float* __restrict__ W1, const float* __restrict__ W2,
                       const float* __restrict__ W3, u16* __restrict__ Wt1,
                       u16* __restrict__ Wt2, u16* __restrict__ Wt3) {
  int i = blockIdx.x * blockDim.x + threadIdx.x;
  float w;
  u16* dst;
  int idx;
  if (i < 8192) {                       // W1 [64,128] -> Wt1 [128][64]
    int c = i >> 6, k = i & 63;
    w = W1[k * 128 + c];
    dst = Wt1; idx = i;
  } else if (i < 24576) {               // W2 [128,128] -> Wt2 [128][128]
    int j = i - 8192;
    int c = j >> 7, k = j & 127;
    w = W2[k * 128 + c];
    dst = Wt2; idx = j;
  } else if (i < 32768) {               // W3 [128,64] -> Wt3 [64][128]
    int j = i - 24576;
    int c = j >> 7, k = j & 127;
    w = W3[k * 64 + c];
    dst = Wt3; idx = j;
  } else {
    return;
  }
  dst[idx] = f2b(w);
}

// ---------------- x fp32 -> bf16 ----------------

__global__ void conv_x(const float* __restrict__ x, u16* __restrict__ xb, int n8) {
  int i = blockIdx.x * blockDim.x + threadIdx.x;
  if (i >= n8) return;
  const float4* p = reinterpret_cast<const float4*>(x) + (size_t)i * 2;
  float4 a = p[0], b = p[1];
  uint4 o;
  o.x = pack2(a.x, a.y);
  o.y = pack2(a.z, a.w);
  o.z = pack2(b.x, b.y);
  o.w = pack2(b.z, b.w);
  *reinterpret_cast<uint4*>(xb + (size_t)i * 8) = o;
}

// ---------------- aggregation: 16 lanes per node, pipelined quad gathers ----------------
// colew: interleaved {col, ew} -> one load yields index+weight (one stream).
// NOTE r18: masked-quad (padded 4-slot) variant REGRESSED — keep
// pipelined-quad + scalar tail.

template <int EPL> struct Raw;
template <> struct Raw<8> { uint4 v; };
template <> struct Raw<4> { uint2 v; };

template <int EPL>
__device__ __forceinline__ Raw<EPL> ldraw(const u16* p);
template <>
__device__ __forceinline__ Raw<8> ldraw<8>(const u16* p) {
  return {*reinterpret_cast<const uint4*>(p)};
}
template <>
__device__ __forceinline__ Raw<4> ldraw<4>(const u16* p) {
  return {*reinterpret_cast<const uint2*>(p)};
}

template <int EPL>
__device__ __forceinline__ void rfma(float* a, float w, Raw<EPL> r) {
  if constexpr (EPL == 8) {
    a[0] += w * asf(r.v.x << 16); a[1] += w * asf(r.v.x & 0xFFFF0000u);
    a[2] += w * asf(r.v.y << 16); a[3] += w * asf(r.v.y & 0xFFFF0000u);
    a[4] += w * asf(r.v.z << 16); a[5] += w * asf(r.v.z & 0xFFFF0000u);
    a[6] += w * asf(r.v.w << 16); a[7] += w * asf(r.v.w & 0xFFFF0000u);
  } else {
    a[0] += w * asf(r.v.x << 16); a[1] += w * asf(r.v.x & 0xFFFF0000u);
    a[2] += w * asf(r.v.y << 16); a[3] += w * asf(r.v.y & 0xFFFF0000u);
  }
}

template <int F, bool BR>  // F = 64 or 128; bf16 in/out
__global__ __launch_bounds__(256) void agg_kernel(const u16* __restrict__ v,
                                                  const float* __restrict__ dinv,
                                                  const int* __restrict__ rowstart,
                                                  const uint2* __restrict__ colew,
                                                  const float* __restrict__ bias,
                                                  u16* __restrict__ out, int n) {
  constexpr int EPL = F / 16;
  const int node = (int)((blockIdx.x * blockDim.x + threadIdx.x) >> 4);
  const int l = threadIdx.x & 15;
  if (node >= n) return;
  const size_t loff = (size_t)l * EPL;
  float acc[EPL];
#pragma unroll
  for (int j = 0; j < EPL; ++j) acc[j] = 0.0f;
  const float di = dinv[node];
  rfma<EPL>(acc, di * di, ldraw<EPL>(v + (size_t)node * F + loff));

  int k = rowstart[node];
  const int r1 = rowstart[node + 1];
  if (k + 4 <= r1) {
    uint2 a0 = colew[k], a1 = colew[k + 1], a2 = colew[k + 2], a3 = colew[k + 3];
    k += 4;
    while (k + 4 <= r1) {
      Raw<EPL> g0 = ldraw<EPL>(v + (size_t)a0.x * F + loff);
      Raw<EPL> g1 = ldraw<EPL>(v + (size_t)a1.x * F + loff);
      Raw<EPL> g2 = ldraw<EPL>(v + (size_t)a2.x * F + loff);
      Raw<EPL> g3 = ldraw<EPL>(v + (size_t)a3.x * F + loff);
      uint2 b0 = colew[k], b1 = colew[k + 1], b2 = colew[k + 2], b3 = colew[k + 3];
      rfma<EPL>(acc, asf(a0.y), g0);
      rfma<EPL>(acc, asf(a1.y), g1);
      rfma<EPL>(acc, asf(a2.y), g2);
      rfma<EPL>(acc, asf(a3.y), g3);
      a0 = b0; a1 = b1; a2 = b2; a3 = b3;
      k += 4;
    }
    Raw<EPL> g0 = ldraw<EPL>(v + (size_t)a0.x * F + loff);
    Raw<EPL> g1 = ldraw<EPL>(v + (size_t)a1.x * F + loff);
    Raw<EPL> g2 = ldraw<EPL>(v + (size_t)a2.x * F + loff);
    Raw<EPL> g3 = ldraw<EPL>(v + (size_t)a3.x * F + loff);
    rfma<EPL>(acc, asf(a0.y), g0);
    rfma<EPL>(acc, asf(a1.y), g1);
    rfma<EPL>(acc, asf(a2.y), g2);
    rfma<EPL>(acc, asf(a3.y), g3);
  }
  for (; k < r1; ++k) {
    uint2 ce = colew[k];
    Raw<EPL> g = ldraw<EPL>(v + (size_t)ce.x * F + loff);
    rfma<EPL>(acc, asf(ce.y), g);
  }

  if (BR) {
#pragma unroll
    for (int j = 0; j < EPL; ++j) acc[j] = fmaxf(acc[j] + bias[l * EPL + j], 0.0f);
  }
  if constexpr (EPL == 8) {
    uint4 o;
    o.x = pack2(acc[0], acc[1]);
    o.y = pack2(acc[2], acc[3]);
    o.z = pack2(acc[4], acc[5]);
    o.w = pack2(acc[6], acc[7]);
    *reinterpret_cast<uint4*>(out + (size_t)node * F + loff) = o;
  } else {
    uint2 o;
    o.x = pack2(acc[0], acc[1]);
    o.y = pack2(acc[2], acc[3]);
    *reinterpret_cast<uint2*>(out + (size_t)node * F + loff) = o;
  }
}

// ---------------- graph boundaries (batch sorted) + segmented mean pool ----------------

__global__ void gbounds_kernel(const int* __restrict__ batch, int* __restrict__ gstart,
                               int N, int G) {
  int g = blockIdx.x * blockDim.x + threadIdx.x;
  if (g > G) return;
  int lo = 0, hi = N;
  while (lo < hi) {
    int mid = (lo + hi) >> 1;
    if (batch[mid] < g) lo = mid + 1; else hi = mid;
  }
  gstart[g] = lo;
}

__global__ __launch_bounds__(256) void pool_kernel(const u16* __restrict__ h3,
                                                   const int* __restrict__ gstart,
                                                   float* __restrict__ pooled, int G) {
  int g = (blockIdx.x * blockDim.x + threadIdx.x) >> 6;
  int lane = threadIdx.x & 63;
  if (g >= G) return;
  int s = gstart[g], e = gstart[g + 1];
  float a0 = 0.f, a1 = 0.f, a2 = 0.f, a3 = 0.f;
  int i = s;
  for (; i + 4 <= e; i += 4) {
    a0 += b2f(h3[(size_t)(i + 0) * 64 + lane]);
    a1 += b2f(h3[(size_t)(i + 1) * 64 + lane]);
    a2 += b2f(h3[(size_t)(i + 2) * 64 + lane]);
    a3 += b2f(h3[(size_t)(i + 3) * 64 + lane]);
  }
  for (; i < e; ++i) a0 += b2f(h3[(size_t)i * 64 + lane]);
  float acc = (a0 + a1) + (a2 + a3);
  pooled[(size_t)g * 64 + lane] = acc / fmaxf((float)(e - s), 1.0f);
}

// ---------------- MFMA GEMM: out = A @ W + bias (+relu) ----------
// r13 config (best measured): 256 thr / 4 waves, __launch_bounds__(256,2),
// 128-row tile, grid-stride, hi-only bf16 W in typed LDS (XOR-swizzled),
// LDS out-staging epilogue with uint4 16B global stores.

template <int K, int NC, bool RELU>
__global__ __launch_bounds__(256, 2) void gemm_mfma(const u16* __restrict__ A,
                                                    const u16* __restrict__ Wt,
                                                    const float* __restrict__ bias,
                                                    u16* __restrict__ out, int n) {
  constexpr int CHK = K / 8;        // 16B chunks per W row
  constexpr int OST = NC + 8;       // padded out-stage row stride (u16)
  __shared__ bf16x8 Wl8[NC * CHK];
  __shared__ float biasl[NC];
  __shared__ u16 obuf[4 * 16 * OST];
  for (int i = threadIdx.x; i < NC * CHK; i += 256) {
    int c = i / CHK, kc = i - c * CHK;
    uint4 raw = *reinterpret_cast<const uint4*>(Wt + (size_t)c * K + kc * 8);
    Wl8[c * CHK + (kc ^ (c & 7))] = __builtin_bit_cast(bf16x8, raw);
  }
  if (threadIdx.x < NC) biasl[threadIdx.x] = bias ? bias[threadIdx.x] : 0.0f;
  __syncthreads();

  const int wid = threadIdx.x >> 6;   // 0..3
  const int lane = threadIdx.x & 63;
  const int lr = lane & 15;
  const int lg = lane >> 4;           // 0..3
  const int ntiles = DIV_UP(n, 128);
  u16* ob = obuf + wid * (16 * OST);

  for (int t = blockIdx.x; t < ntiles; t += (int)gridDim.x) {
    const int row0 = t * 128 + wid * 32;

    bf16x8 af[2][K / 32];
#pragma unroll
    for (int rep = 0; rep < 2; ++rep) {
      int ar = row0 + rep * 16 + lr;
      if (ar >= n) ar = n - 1;  // clamp; stores guarded
      const u16* ap = A + (size_t)ar * K + lg * 8;
#pragma unroll
      for (int ks = 0; ks < K / 32; ++ks) af[rep][ks] = *reinterpret_cast<const bf16x8*>(ap + ks * 32);
    }

    f32x4 acc[2][NC / 16];
#pragma unroll
    for (int rep = 0; rep < 2; ++rep)
#pragma unroll
      for (int ct = 0; ct < NC / 16; ++ct) acc[rep][ct] = {0.f, 0.f, 0.f, 0.f};

#pragma unroll
    for (int ks = 0; ks < K / 32; ++ks) {
#pragma unroll
      for (int ct = 0; ct < NC / 16; ++ct) {
        const int c = ct * 16 + lr;
        const int slot = (ks * 4 + lg) ^ (c & 7);
        bf16x8 bh = Wl8[c * CHK + slot];
        acc[0][ct] = __builtin_amdgcn_mfma_f32_16x16x32_bf16(af[0][ks], bh, acc[0][ct], 0, 0, 0);
        acc[1][ct] = __builtin_amdgcn_mfma_f32_16x16x32_bf16(af[1][ks], bh, acc[1][ct], 0, 0, 0);
      }
    }

#pragma unroll
    for (int rep = 0; rep < 2; ++rep) {
      // stage this rep's 16 x NC tile into LDS (scalar u16 writes, no vmcnt)
#pragma unroll
      for (int ct = 0; ct < NC / 16; ++ct) {
        const int c = ct * 16 + lr;
        const float b = biasl[c];
#pragma unroll
        for (int v = 0; v < 4; ++v) {
          float o = acc[rep][ct][v] + b;
          if (RELU) o = fmaxf(o, 0.0f);
          ob[(lg * 4 + v) * OST + c] = f2b(o);
        }
      }
      asm volatile("s_waitcnt lgkmcnt(0)" ::: "memory");
      // read back row-major, wide 16B global stores
      const int rrow = lane >> 2;   // 0..15
      const int chk0 = lane & 3;    // 0..3
      const int grow = row0 + rep * 16 + rrow;
      if (grow < n) {
        u16* gp = out + (size_t)grow * NC;
#pragma unroll
        for (int it = 0; it < NC / 32; ++it) {
          const int ch = it * 4 + chk0;
          uint4 val = *reinterpret_cast<const uint4*>(ob + rrow * OST + ch * 8);
          *reinterpret_cast<uint4*>(gp + ch * 8) = val;
        }
      }
      asm volatile("s_waitcnt lgkmcnt(0)" ::: "memory");
    }
  }
}

// ---------------- 5-task MLP heads ----------------

__global__ __launch_bounds__(256) void heads_kernel(const float* __restrict__ pooled,
                                                    const float* __restrict__ Wa,
                                                    const float* __restrict__ ba,
                                                    const float* __restrict__ Wb,
                                                    const float* __restrict__ bb,
                                                    float* __restrict__ outp, int G) {
  int gid = blockIdx.x * blockDim.x + threadIdx.x;
  if (gid >= 5 * G) return;
  int g = gid % G;
  int t = gid / G;
  const float* Wat = Wa + (size_t)t * 64 * 32;
  float hid[32];
#pragma unroll
  for (int j = 0; j < 32; ++j) hid[j] = ba[t * 32 + j];
  for (int d = 0; d < 64; ++d) {
    float pd = pooled[(size_t)g * 64 + d];
#pragma unroll
    for (int j = 0; j < 32; ++j) hid[j] += pd * Wat[d * 32 + j];
  }
  float o = bb[t];
#pragma unroll
  for (int j = 0; j < 32; ++j) o += fmaxf(hid[j], 0.0f) * Wb[t * 32 + j];
  outp[(size_t)t * G + g] = o;
}

// ---------------- launch ----------------

extern "C" void kernel_launch(void* const* d_in, const int* in_sizes, int n_in,
                              void* d_out, int out_size, void* d_ws, size_t ws_size,
                              hipStream_t stream) {
  (void)n_in;
  (void)ws_size;
  const float* x  = (const float*)d_in[0];
  const int* ei   = (const int*)d_in[1];
  const int* batch = (const int*)d_in[2];
  const float* W1 = (const float*)d_in[3];
  const float* b1 = (const float*)d_in[4];
  const float* W2 = (const float*)d_in[5];
  const float* b2 = (const float*)d_in[6];
  const float* W3 = (const float*)d_in[7];
  const float* b3 = (const float*)d_in[8];
  const float* Wa = (const float*)d_in[9];
  const float* ba = (const float*)d_in[10];
  const float* Wb = (const float*)d_in[11];
  const float* bb = (const float*)d_in[12];
  float* out = (float*)d_out;

  const int N = in_sizes[0] / 64;
  const int E = in_sizes[1] / 2;
  const int G = out_size / 5;
  const int* src = ei;
  const int* dst = ei + E;

  char* ws = (char*)d_ws;
  size_t off = 0;
  auto alloc = [&](size_t bytes) -> char* {
    char* p = ws + off;
    off = (off + bytes + 255) & ~(size_t)255;
    return p;
  };
  int* cnt      = (int*)alloc((size_t)N * 4);
  int* rowstart = (int*)alloc((size_t)(N + 1) * 4);
  int* rank     = (int*)alloc((size_t)E * 4);
  uint2* colew  = (uint2*)alloc((size_t)E * 8);
  float* dinv   = (float*)alloc((size_t)N * 4);
  const int nchunks = DIV_UP(N, 1024);  // 391 for N=400000 (<= 512)
  int* bsums    = (int*)alloc((size_t)nchunks * 4);
  int* gstart   = (int*)alloc((size_t)(G + 1) * 4);
  float* pooled = (float*)alloc((size_t)G * 64 * 4);
  u16* Wt1      = (u16*)alloc(8192 * 2);
  u16* Wt2      = (u16*)alloc(16384 * 2);
  u16* Wt3      = (u16*)alloc(8192 * 2);
  const size_t act_elems = (size_t)N * 128;
  u16* bufA     = (u16*)alloc(act_elems * 2);
  u16* bufB     = (u16*)alloc(act_elems * 2);

  hipMemsetAsync(cnt, 0, (size_t)N * 4, stream);

  count_kernel<<<DIV_UP(E, 256), 256, 0, stream>>>(dst, cnt, rank, E);
  scan1_kernel<<<nchunks, 256, 0, stream>>>(cnt, rowstart, bsums, N);
  scan2_kernel<<<1, 512, 0, stream>>>(bsums, nchunks);
  scan3_kernel<<<DIV_UP(N, 256), 256, 0, stream>>>(rowstart, bsums, cnt, dinv, N, E);
  fill_kernel<<<DIV_UP(E, 256), 256, 0, stream>>>(src, dst, rank, rowstart, dinv, colew, E);
  prep_w<<<128, 256, 0, stream>>>(W1, W2, W3, Wt1, Wt2, Wt3);
  gbounds_kernel<<<DIV_UP(G + 1, 256), 256, 0, stream>>>(batch, gstart, N, G);

  // xb (bf16 x) lives in bufA's first N*64 entries (dead before h1 is written).
  u16* xb = bufA;
  conv_x<<<DIV_UP(N * 8, 256), 256, 0, stream>>>(x, xb, N * 8);

  const int aggblocks = DIV_UP(N, 16);
  // t1 [N,64] in bufB; h1 [N,128] in bufA; t2 [N,128] in bufB; h2 [N,128] in bufA;
  // hw3 [N,64] in bufB; h3 [N,64] in bufA.
  agg_kernel<64, false><<<aggblocks, 256, 0, stream>>>(
      xb, dinv, rowstart, colew, nullptr, bufB, N);
  gemm_mfma<64, 128, true><<<512, 256, 0, stream>>>(bufB, Wt1, b1, bufA, N);
  agg_kernel<128, false><<<aggblocks, 256, 0, stream>>>(
      bufA, dinv, rowstart, colew, nullptr, bufB, N);
  gemm_mfma<128, 128, true><<<512, 256, 0, stream>>>(bufB, Wt2, b2, bufA, N);
  gemm_mfma<128, 64, false><<<512, 256, 0, stream>>>(bufA, Wt3, nullptr, bufB, N);
  agg_kernel<64, true><<<aggblocks, 256, 0, stream>>>(
      bufB, dinv, rowstart, colew, b3, bufA, N);
  pool_kernel<<<DIV_UP(G, 4), 256, 0, stream>>>(bufA, gstart, pooled, G);
  heads_kernel<<<DIV_UP(5 * G, 256), 256, 0, stream>>>(pooled, Wa, ba, Wb, bb, out, G);
}

// Round 20
// 501.438 us; speedup vs baseline: 1.0697x; 1.0392x over previous
//
#include <hip/hip_runtime.h>
#include <cstdint>
#include <cstddef>

#define DIV_UP(a, b) (((a) + (b) - 1) / (b))

typedef unsigned short u16;
typedef __attribute__((ext_vector_type(8))) short bf16x8;
typedef __attribute__((ext_vector_type(4))) float f32x4;

// ---------------- bf16 helpers (RNE) ----------------

__device__ __forceinline__ float asf(unsigned int u) {
  float f;
  __builtin_memcpy(&f, &u, 4);
  return f;
}
__device__ __forceinline__ unsigned int asu(float f) {
  unsigned int u;
  __builtin_memcpy(&u, &f, 4);
  return u;
}
__device__ __forceinline__ float b2f(u16 u) { return asf(((unsigned int)u) << 16); }
__device__ __forceinline__ u16 f2b(float f) {
  unsigned int x = asu(f);
  return (u16)((x + 0x7FFFu + ((x >> 16) & 1u)) >> 16);
}
__device__ __forceinline__ unsigned int pack2(float lo, float hi) {
  return ((unsigned int)f2b(hi) << 16) | (unsigned int)f2b(lo);
}

// ---------------- CSR build ----------------

// rank[e] = this edge's arrival order within its dst bucket (the atomic's
// return value). All atomic work lives here; fill is atomic-free.
// NOTE r18: 4-edge strided ILP here REGRESSED (broke dst coalescing).
__global__ void count_kernel(const int* __restrict__ dst, int* __restrict__ cnt,
                             int* __restrict__ rank, int E) {
  int e = blockIdx.x * blockDim.x + threadIdx.x;
  if (e < E) rank[e] = atomicAdd(&cnt[dst[e]], 1);
}

__global__ void scan1_kernel(const int* __restrict__ cnt, int* __restrict__ rowstart,
                             int* __restrict__ bsums, int n) {
  __shared__ int sh[256];
  const int tid = threadIdx.x;
  const int base = blockIdx.x * 1024 + tid * 4;
  int c0 = (base + 0 < n) ? cnt[base + 0] : 0;
  int c1 = (base + 1 < n) ? cnt[base + 1] : 0;
  int c2 = (base + 2 < n) ? cnt[base + 2] : 0;
  int c3 = (base + 3 < n) ? cnt[base + 3] : 0;
  sh[tid] = c0 + c1 + c2 + c3;
  __syncthreads();
  for (int off = 1; off < 256; off <<= 1) {
    int v = (tid >= off) ? sh[tid - off] : 0;
    __syncthreads();
    sh[tid] += v;
    __syncthreads();
  }
  int excl = (tid > 0) ? sh[tid - 1] : 0;
  if (base + 0 < n) rowstart[base + 0] = excl;
  if (base + 1 < n) rowstart[base + 1] = excl + c0;
  if (base + 2 < n) rowstart[base + 2] = excl + c0 + c1;
  if (base + 3 < n) rowstart[base + 3] = excl + c0 + c1 + c2;
  if (tid == 255) bsums[blockIdx.x] = sh[255];
}

__global__ void scan2_kernel(int* __restrict__ bsums, int nb) {
  __shared__ int sh[512];
  const int tid = threadIdx.x;
  int v = (tid < nb) ? bsums[tid] : 0;
  sh[tid] = v;
  __syncthreads();
  for (int off = 1; off < 512; off <<= 1) {
    int t = (tid >= off) ? sh[tid - off] : 0;
    __syncthreads();
    sh[tid] += t;
    __syncthreads();
  }
  int excl = (tid > 0) ? sh[tid - 1] : 0;
  if (tid < nb) bsums[tid] = excl;
}

__global__ void scan3_kernel(int* __restrict__ rowstart, const int* __restrict__ bsums,
                             const int* __restrict__ cnt, float* __restrict__ dinv,
                             int n, int E) {
  int i = blockIdx.x * blockDim.x + threadIdx.x;
  if (i < n) {
    rowstart[i] = rowstart[i] + bsums[i >> 10];
    dinv[i] = rsqrtf((float)cnt[i] + 1.0f);  // +1 for self-loop
  }
  if (i == 0) rowstart[n] = E;
}

// atomic-free: pos = rowstart[d] + rank[e]; one fire-and-forget 8B scatter.
__global__ void fill_kernel(const int* __restrict__ src, const int* __restrict__ dst,
                            const int* __restrict__ rank, const int* __restrict__ rowstart,
                            const float* __restrict__ dinv, uint2* __restrict__ colew,
                            int E) {
  int e = blockIdx.x * blockDim.x + threadIdx.x;
  if (e < E) {
    int s = src[e], d = dst[e];
    float w = dinv[s] * dinv[d];
    int pos = rowstart[d] + rank[e];
    colew[pos] = make_uint2((unsigned int)s, asu(w));
  }
}

// ---------------- W prep: fp32 [K,NC] -> transposed bf16 [NC*K] ----------------

__global__ void prep_w(const float* __restrict__ W1, const float* __restrict__ W2,
                       const float* __restrict__ W3, u16* __restrict__ Wt1,
                       u16* __restrict__ Wt2, u16* __restrict__ Wt3) {
  int i = blockIdx.x * blockDim.x + threadIdx.x;
  float w;
  u16* dst;
  int idx;
  if (i < 8192) {                       // W1 [64,128] -> Wt1 [128][64]
    int c = i >> 6, k = i & 63;
    w = W1[k * 128 + c];
    dst = Wt1; idx = i;
  } else if (i < 24576) {               // W2 [128,128] -> Wt2 [128][128]
    int j = i - 8192;
    int c = j >> 7, k = j & 127;
    w = W2[k * 128 + c];
    dst = Wt2; idx = j;
  } else if (i < 32768) {               // W3 [128,64] -> Wt3 [64][128]
    int j = i - 24576;
    int c = j >> 7, k = j & 127;
    w = W3[k * 64 + c];
    dst = Wt3; idx = j;
  } else {
    return;
  }
  dst[idx] = f2b(w);
}

// ---------------- x fp32 -> bf16 ----------------

__global__ void conv_x(const float* __restrict__ x, u16* __restrict__ xb, int n8) {
  int i = blockIdx.x * blockDim.x + threadIdx.x;
  if (i >= n8) return;
  const float4* p = reinterpret_cast<const float4*>(x) + (size_t)i * 2;
  float4 a = p[0], b = p[1];
  uint4 o;
  o.x = pack2(a.x, a.y);
  o.y = pack2(a.z, a.w);
  o.z = pack2(b.x, b.y);
  o.w = pack2(b.z, b.w);
  *reinterpret_cast<uint4*>(xb + (size_t)i * 8) = o;
}

// ---------------- aggregation: LPN lanes per node, pipelined quad gathers ----------------
// F=64 -> LPN=8 (8 lanes x 16B: full-width loads, 8 node-groups/wave = 2x
// outstanding gathers vs 16-lane version whose uint2 loads were 8B/lane).
// F=128 -> LPN=16 (16 lanes x 16B, measured-good). EPL = 8 floats/lane both.
// colew: interleaved {col, ew} -> one load yields index+weight.
// NOTE r18: masked-quad padding REGRESSED — keep pipelined-quad + tail.

struct Raw8 { uint4 v; };
__device__ __forceinline__ Raw8 ldraw8(const u16* p) {
  return {*reinterpret_cast<const uint4*>(p)};
}
__device__ __forceinline__ void rfma8(float* a, float w, Raw8 r) {
  a[0] += w * asf(r.v.x << 16); a[1] += w * asf(r.v.x & 0xFFFF0000u);
  a[2] += w * asf(r.v.y << 16); a[3] += w * asf(r.v.y & 0xFFFF0000u);
  a[4] += w * asf(r.v.z << 16); a[5] += w * asf(r.v.z & 0xFFFF0000u);
  a[6] += w * asf(r.v.w << 16); a[7] += w * asf(r.v.w & 0xFFFF0000u);
}

template <int F, int LPN, bool BR>  // LPN*8 == F
__global__ __launch_bounds__(256) void agg_kernel(const u16* __restrict__ v,
                                                  const float* __restrict__ dinv,
                                                  const int* __restrict__ rowstart,
                                                  const uint2* __restrict__ colew,
                                                  const float* __restrict__ bias,
                                                  u16* __restrict__ out, int n) {
  const int node = (int)((blockIdx.x * blockDim.x + threadIdx.x) / LPN);
  const int l = (int)(threadIdx.x % LPN);
  if (node >= n) return;
  const size_t loff = (size_t)l * 8;
  float acc[8];
#pragma unroll
  for (int j = 0; j < 8; ++j) acc[j] = 0.0f;
  const float di = dinv[node];
  rfma8(acc, di * di, ldraw8(v + (size_t)node * F + loff));

  int k = rowstart[node];
  const int r1 = rowstart[node + 1];
  if (k + 4 <= r1) {
    uint2 a0 = colew[k], a1 = colew[k + 1], a2 = colew[k + 2], a3 = colew[k + 3];
    k += 4;
    while (k + 4 <= r1) {
      Raw8 g0 = ldraw8(v + (size_t)a0.x * F + loff);
      Raw8 g1 = ldraw8(v + (size_t)a1.x * F + loff);
      Raw8 g2 = ldraw8(v + (size_t)a2.x * F + loff);
      Raw8 g3 = ldraw8(v + (size_t)a3.x * F + loff);
      uint2 b0 = colew[k], b1 = colew[k + 1], b2 = colew[k + 2], b3 = colew[k + 3];
      rfma8(acc, asf(a0.y), g0);
      rfma8(acc, asf(a1.y), g1);
      rfma8(acc, asf(a2.y), g2);
      rfma8(acc, asf(a3.y), g3);
      a0 = b0; a1 = b1; a2 = b2; a3 = b3;
      k += 4;
    }
    Raw8 g0 = ldraw8(v + (size_t)a0.x * F + loff);
    Raw8 g1 = ldraw8(v + (size_t)a1.x * F + loff);
    Raw8 g2 = ldraw8(v + (size_t)a2.x * F + loff);
    Raw8 g3 = ldraw8(v + (size_t)a3.x * F + loff);
    rfma8(acc, asf(a0.y), g0);
    rfma8(acc, asf(a1.y), g1);
    rfma8(acc, asf(a2.y), g2);
    rfma8(acc, asf(a3.y), g3);
  }
  for (; k < r1; ++k) {
    uint2 ce = colew[k];
    Raw8 g = ldraw8(v + (size_t)ce.x * F + loff);
    rfma8(acc, asf(ce.y), g);
  }

  if (BR) {
#pragma unroll
    for (int j = 0; j < 8; ++j) acc[j] = fmaxf(acc[j] + bias[l * 8 + j], 0.0f);
  }
  uint4 o;
  o.x = pack2(acc[0], acc[1]);
  o.y = pack2(acc[2], acc[3]);
  o.z = pack2(acc[4], acc[5]);
  o.w = pack2(acc[6], acc[7]);
  *reinterpret_cast<uint4*>(out + (size_t)node * F + loff) = o;
}

// ---------------- graph boundaries (batch sorted) + segmented mean pool ----------------

__global__ void gbounds_kernel(const int* __restrict__ batch, int* __restrict__ gstart,
                               int N, int G) {
  int g = blockIdx.x * blockDim.x + threadIdx.x;
  if (g > G) return;
  int lo = 0, hi = N;
  while (lo < hi) {
    int mid = (lo + hi) >> 1;
    if (batch[mid] < g) lo = mid + 1; else hi = mid;
  }
  gstart[g] = lo;
}

__global__ __launch_bounds__(256) void pool_kernel(const u16* __restrict__ h3,
                                                   const int* __restrict__ gstart,
                                                   float* __restrict__ pooled, int G) {
  int g = (blockIdx.x * blockDim.x + threadIdx.x) >> 6;
  int lane = threadIdx.x & 63;
  if (g >= G) return;
  int s = gstart[g], e = gstart[g + 1];
  float a0 = 0.f, a1 = 0.f, a2 = 0.f, a3 = 0.f;
  int i = s;
  for (; i + 4 <= e; i += 4) {
    a0 += b2f(h3[(size_t)(i + 0) * 64 + lane]);
    a1 += b2f(h3[(size_t)(i + 1) * 64 + lane]);
    a2 += b2f(h3[(size_t)(i + 2) * 64 + lane]);
    a3 += b2f(h3[(size_t)(i + 3) * 64 + lane]);
  }
  for (; i < e; ++i) a0 += b2f(h3[(size_t)i * 64 + lane]);
  float acc = (a0 + a1) + (a2 + a3);
  pooled[(size_t)g * 64 + lane] = acc / fmaxf((float)(e - s), 1.0f);
}

// ---------------- MFMA GEMM: out = A @ W + bias (+relu) ----------
// r13 config (best measured): 256 thr / 4 waves, __launch_bounds__(256,2),
// 128-row tile, grid-stride, hi-only bf16 W in typed LDS (XOR-swizzled),
// LDS out-staging epilogue with uint4 16B global stores.

template <int K, int NC, bool RELU>
__global__ __launch_bounds__(256, 2) void gemm_mfma(const u16* __restrict__ A,
                                                    const u16* __restrict__ Wt,
                                                    const float* __restrict__ bias,
                                                    u16* __restrict__ out, int n) {
  constexpr int CHK = K / 8;        // 16B chunks per W row
  constexpr int OST = NC + 8;       // padded out-stage row stride (u16)
  __shared__ bf16x8 Wl8[NC * CHK];
  __shared__ float biasl[NC];
  __shared__ u16 obuf[4 * 16 * OST];
  for (int i = threadIdx.x; i < NC * CHK; i += 256) {
    int c = i / CHK, kc = i - c * CHK;
    uint4 raw = *reinterpret_cast<const uint4*>(Wt + (size_t)c * K + kc * 8);
    Wl8[c * CHK + (kc ^ (c & 7))] = __builtin_bit_cast(bf16x8, raw);
  }
  if (threadIdx.x < NC) biasl[threadIdx.x] = bias ? bias[threadIdx.x] : 0.0f;
  __syncthreads();

  const int wid = threadIdx.x >> 6;   // 0..3
  const int lane = threadIdx.x & 63;
  const int lr = lane & 15;
  const int lg = lane >> 4;           // 0..3
  const int ntiles = DIV_UP(n, 128);
  u16* ob = obuf + wid * (16 * OST);

  for (int t = blockIdx.x; t < ntiles; t += (int)gridDim.x) {
    const int row0 = t * 128 + wid * 32;

    bf16x8 af[2][K / 32];
#pragma unroll
    for (int rep = 0; rep < 2; ++rep) {
      int ar = row0 + rep * 16 + lr;
      if (ar >= n) ar = n - 1;  // clamp; stores guarded
      const u16* ap = A + (size_t)ar * K + lg * 8;
#pragma unroll
      for (int ks = 0; ks < K / 32; ++ks) af[rep][ks] = *reinterpret_cast<const bf16x8*>(ap + ks * 32);
    }

    f32x4 acc[2][NC / 16];
#pragma unroll
    for (int rep = 0; rep < 2; ++rep)
#pragma unroll
      for (int ct = 0; ct < NC / 16; ++ct) acc[rep][ct] = {0.f, 0.f, 0.f, 0.f};

#pragma unroll
    for (int ks = 0; ks < K / 32; ++ks) {
#pragma unroll
      for (int ct = 0; ct < NC / 16; ++ct) {
        const int c = ct * 16 + lr;
        const int slot = (ks * 4 + lg) ^ (c & 7);
        bf16x8 bh = Wl8[c * CHK + slot];
        acc[0][ct] = __builtin_amdgcn_mfma_f32_16x16x32_bf16(af[0][ks], bh, acc[0][ct], 0, 0, 0);
        acc[1][ct] = __builtin_amdgcn_mfma_f32_16x16x32_bf16(af[1][ks], bh, acc[1][ct], 0, 0, 0);
      }
    }

#pragma unroll
    for (int rep = 0; rep < 2; ++rep) {
      // stage this rep's 16 x NC tile into LDS (scalar u16 writes, no vmcnt)
#pragma unroll
      for (int ct = 0; ct < NC / 16; ++ct) {
        const int c = ct * 16 + lr;
        const float b = biasl[c];
#pragma unroll
        for (int v = 0; v < 4; ++v) {
          float o = acc[rep][ct][v] + b;
          if (RELU) o = fmaxf(o, 0.0f);
          ob[(lg * 4 + v) * OST + c] = f2b(o);
        }
      }
      asm volatile("s_waitcnt lgkmcnt(0)" ::: "memory");
      // read back row-major, wide 16B global stores
      const int rrow = lane >> 2;   // 0..15
      const int chk0 = lane & 3;    // 0..3
      const int grow = row0 + rep * 16 + rrow;
      if (grow < n) {
        u16* gp = out + (size_t)grow * NC;
#pragma unroll
        for (int it = 0; it < NC / 32; ++it) {
          const int ch = it * 4 + chk0;
          uint4 val = *reinterpret_cast<const uint4*>(ob + rrow * OST + ch * 8);
          *reinterpret_cast<uint4*>(gp + ch * 8) = val;
        }
      }
      asm volatile("s_waitcnt lgkmcnt(0)" ::: "memory");
    }
  }
}

// ---------------- 5-task MLP heads ----------------

__global__ __launch_bounds__(256) void heads_kernel(const float* __restrict__ pooled,
                                                    const float* __restrict__ Wa,
                                                    const float* __restrict__ ba,
                                                    const float* __restrict__ Wb,
                                                    const float* __restrict__ bb,
                                                    float* __restrict__ outp, int G) {
  int gid = blockIdx.x * blockDim.x + threadIdx.x;
  if (gid >= 5 * G) return;
  int g = gid % G;
  int t = gid / G;
  const float* Wat = Wa + (size_t)t * 64 * 32;
  float hid[32];
#pragma unroll
  for (int j = 0; j < 32; ++j) hid[j] = ba[t * 32 + j];
  for (int d = 0; d < 64; ++d) {
    float pd = pooled[(size_t)g * 64 + d];
#pragma unroll
    for (int j = 0; j < 32; ++j) hid[j] += pd * Wat[d * 32 + j];
  }
  float o = bb[t];
#pragma unroll
  for (int j = 0; j < 32; ++j) o += fmaxf(hid[j], 0.0f) * Wb[t * 32 + j];
  outp[(size_t)t * G + g] = o;
}

// ---------------- launch ----------------

extern "C" void kernel_launch(void* const* d_in, const int* in_sizes, int n_in,
                              void* d_out, int out_size, void* d_ws, size_t ws_size,
                              hipStream_t stream) {
  (void)n_in;
  (void)ws_size;
  const float* x  = (const float*)d_in[0];
  const int* ei   = (const int*)d_in[1];
  const int* batch = (const int*)d_in[2];
  const float* W1 = (const float*)d_in[3];
  const float* b1 = (const float*)d_in[4];
  const float* W2 = (const float*)d_in[5];
  const float* b2 = (const float*)d_in[6];
  const float* W3 = (const float*)d_in[7];
  const float* b3 = (const float*)d_in[8];
  const float* Wa = (const float*)d_in[9];
  const float* ba = (const float*)d_in[10];
  const float* Wb = (const float*)d_in[11];
  const float* bb = (const float*)d_in[12];
  float* out = (float*)d_out;

  const int N = in_sizes[0] / 64;
  const int E = in_sizes[1] / 2;
  const int G = out_size / 5;
  const int* src = ei;
  const int* dst = ei + E;

  char* ws = (char*)d_ws;
  size_t off = 0;
  auto alloc = [&](size_t bytes) -> char* {
    char* p = ws + off;
    off = (off + bytes + 255) & ~(size_t)255;
    return p;
  };
  int* cnt      = (int*)alloc((size_t)N * 4);
  int* rowstart = (int*)alloc((size_t)(N + 1) * 4);
  int* rank     = (int*)alloc((size_t)E * 4);
  uint2* colew  = (uint2*)alloc((size_t)E * 8);
  float* dinv   = (float*)alloc((size_t)N * 4);
  const int nchunks = DIV_UP(N, 1024);  // 391 for N=400000 (<= 512)
  int* bsums    = (int*)alloc((size_t)nchunks * 4);
  int* gstart   = (int*)alloc((size_t)(G + 1) * 4);
  float* pooled = (float*)alloc((size_t)G * 64 * 4);
  u16* Wt1      = (u16*)alloc(8192 * 2);
  u16* Wt2      = (u16*)alloc(16384 * 2);
  u16* Wt3      = (u16*)alloc(8192 * 2);
  const size_t act_elems = (size_t)N * 128;
  u16* bufA     = (u16*)alloc(act_elems * 2);
  u16* bufB     = (u16*)alloc(act_elems * 2);

  hipMemsetAsync(cnt, 0, (size_t)N * 4, stream);

  count_kernel<<<DIV_UP(E, 256), 256, 0, stream>>>(dst, cnt, rank, E);
  scan1_kernel<<<nchunks, 256, 0, stream>>>(cnt, rowstart, bsums, N);
  scan2_kernel<<<1, 512, 0, stream>>>(bsums, nchunks);
  scan3_kernel<<<DIV_UP(N, 256), 256, 0, stream>>>(rowstart, bsums, cnt, dinv, N, E);
  fill_kernel<<<DIV_UP(E, 256), 256, 0, stream>>>(src, dst, rank, rowstart, dinv, colew, E);
  prep_w<<<128, 256, 0, stream>>>(W1, W2, W3, Wt1, Wt2, Wt3);
  gbounds_kernel<<<DIV_UP(G + 1, 256), 256, 0, stream>>>(batch, gstart, N, G);

  // xb (bf16 x) lives in bufA's first N*64 entries (dead before h1 is written).
  u16* xb = bufA;
  conv_x<<<DIV_UP(N * 8, 256), 256, 0, stream>>>(x, xb, N * 8);

  // t1 [N,64] in bufB; h1 [N,128] in bufA; t2 [N,128] in bufB; h2 [N,128] in bufA;
  // hw3 [N,64] in bufB; h3 [N,64] in bufA.
  agg_kernel<64, 8, false><<<DIV_UP(N, 32), 256, 0, stream>>>(
      xb, dinv, rowstart, colew, nullptr, bufB, N);
  gemm_mfma<64, 128, true><<<512, 256, 0, stream>>>(bufB, Wt1, b1, bufA, N);
  agg_kernel<128, 16, false><<<DIV_UP(N, 16), 256, 0, stream>>>(
      bufA, dinv, rowstart, colew, nullptr, bufB, N);
  gemm_mfma<128, 128, true><<<512, 256, 0, stream>>>(bufB, Wt2, b2, bufA, N);
  gemm_mfma<128, 64, false><<<512, 256, 0, stream>>>(bufA, Wt3, nullptr, bufB, N);
  agg_kernel<64, 8, true><<<DIV_UP(N, 32), 256, 0, stream>>>(
      bufB, dinv, rowstart, colew, b3, bufA, N);
  pool_kernel<<<DIV_UP(G, 4), 256, 0, stream>>>(bufA, gstart, pooled, G);
  heads_kernel<<<DIV_UP(5 * G, 256), 256, 0, stream>>>(pooled, Wa, ba, Wb, bb, out, G);
}